// Round 16
// baseline (418.824 us; speedup 1.0000x reference)
//
#include <hip/hip_runtime.h>
#include <hip/hip_bf16.h>
#include <math.h>

#define N_NODES 100000
#define N_EDGES 1600000
#define ORIG    92
#define NBR     41
#define ATOM    64
#define NCONV   3
#define HFEA    128
#define NGRAPH  256
#define ZD      169           // 2*ATOM + NBR
#define TBINS   5120
#define TMAX    10.0f
#define TS      ((TBINS + 1) * 64)   // per-layer table stride (uints)
#define SP      72                   // nodeP LDS row pad (shorts)
#define SPE     136                  // embed LDS row pad (shorts), K=128
#define LOG2E   1.4426950408889634f
#define LN2     0.6931471805599453f
#define EPS2    (1e-5f / (LN2 * LN2))   // BN eps compensated for un-scaled agg
#define NBKT    391                  // ceil(N_NODES / 256)
#define S1E     6250                 // edges per k_bhist block (256 blocks exact)
#define S3CH    4096                 // edges per k_psort1 block
#define PSLOT   128                  // pstats slots

typedef __attribute__((ext_vector_type(8))) short short8;
typedef __attribute__((ext_vector_type(2))) float f32x2;
typedef __attribute__((ext_vector_type(4))) float f32x4;
typedef __attribute__((ext_vector_type(8))) int int8v;

__device__ __forceinline__ float softplus_f(float x) {
    return fmaxf(x, 0.0f) + log1pf(expf(-fabsf(x)));
}
// fast softplus via exp2/log2 HW ops
__device__ __forceinline__ float sp_fast2(float x) {
    float t = x * LOG2E;
    return LN2 * (fmaxf(t, 0.0f) +
                  __builtin_amdgcn_logf(1.0f + __builtin_amdgcn_exp2f(-fabsf(t))));
}
// pack 2 fp32 -> 2 bf16 in one uint
__device__ __forceinline__ unsigned int pk_bf16(float lo, float hi) {
    unsigned int r;
    asm("v_cvt_pk_bf16_f32 %0, %1, %2" : "=v"(r) : "v"(lo), "v"(hi));
    return r;
}
// dual-f32 packed add (VOP3P)
__device__ __forceinline__ f32x2 pk_addf(f32x2 a, f32x2 b) {
    f32x2 r;
    asm("v_pk_add_f32 %0, %1, %2" : "=v"(r) : "v"(a), "v"(b));
    return r;
}
__device__ __forceinline__ float bf_lo(unsigned int p) { return __uint_as_float(p << 16); }
__device__ __forceinline__ float bf_hi(unsigned int p) { return __uint_as_float(p & 0xffff0000u); }

// ---------- sort pass 0: coarse bucket histogram + last-block scan ----------
__global__ __launch_bounds__(256) void k_bhist(const int* __restrict__ ei,
                                               int* __restrict__ bucketCnt,
                                               int* __restrict__ flag,
                                               int* __restrict__ bucketBase,
                                               int* __restrict__ bucketCursor,
                                               int* __restrict__ offs) {
    __shared__ int cntL[NBKT];
    __shared__ int lastFlag;
    int tid = threadIdx.x;
    for (int i = tid; i < NBKT; i += 256) cntL[i] = 0;
    __syncthreads();
    int base = blockIdx.x * S1E;
    for (int i = tid; i < S1E; i += 256)
        atomicAdd(&cntL[ei[N_EDGES + base + i] >> 8], 1);
    __syncthreads();
    for (int i = tid; i < NBKT; i += 256)
        if (cntL[i]) atomicAdd(&bucketCnt[i], cntL[i]);
    if (tid == 0) {
        __threadfence();
        lastFlag = (atomicAdd(flag, 1) == 255) ? 1 : 0;
    }
    __syncthreads();
    if (lastFlag && tid < 64) {
        __threadfence();
        int carry = 0;
        for (int b0 = 0; b0 < NBKT; b0 += 64) {
            int idx = b0 + tid;
            int v0 = (idx < NBKT) ? bucketCnt[idx] : 0;
            int v = v0;
            for (int d = 1; d < 64; d <<= 1) {
                int u = __shfl_up(v, d, 64);
                if (tid >= d) v += u;
            }
            if (idx < NBKT) {
                int ex = carry + v - v0;
                bucketBase[idx] = ex;
                bucketCursor[idx] = ex;
            }
            carry += __shfl(v, 63, 64);
        }
        if (tid == 0) {
            bucketBase[NBKT] = N_EDGES;
            offs[N_NODES] = N_EDGES;
        }
    }
}

// ---------- sort pass 1: bucket-binned staging, coalesced burst writes ----------
__global__ __launch_bounds__(256) void k_psort1(const int* __restrict__ ei,
                                                const float* __restrict__ ea,
                                                int* __restrict__ bucketCursor,
                                                int2* __restrict__ staging) {
    __shared__ int cntL[NBKT], scanB[NBKT], curL[NBKT], gbaseL[NBKT];
    __shared__ int sortedD[S3CH], sortedN[S3CH];
    int tid = threadIdx.x;
    int base = blockIdx.x * S3CH;
    int myCount = N_EDGES - base;
    if (myCount > S3CH) myCount = S3CH;
    for (int i = tid; i < NBKT; i += 256) { cntL[i] = 0; curL[i] = 0; }
    __syncthreads();
    int descr[16], dstr[16];
#pragma unroll
    for (int j = 0; j < 16; ++j) {
        int i = j * 256 + tid;
        descr[j] = 0; dstr[j] = -1;
        if (i < myCount) {
            int e = base + i;
            int src = ei[e];
            int dst = ei[N_EDGES + e];
            float a = ea[3 * e], bb = ea[3 * e + 1], c = ea[3 * e + 2];
            float d = sqrtf(a * a + bb * bb + c * c);
            int bin = (int)fminf(fmaf(d, (float)TBINS / TMAX, 0.5f), (float)TBINS);
            descr[j] = (bin << 17) | src;
            dstr[j] = dst;
            atomicAdd(&cntL[dst >> 8], 1);
        }
    }
    __syncthreads();
    if (tid < 64) {  // wave 0 exclusive-scans cntL
        int carry = 0;
        for (int b0 = 0; b0 < NBKT; b0 += 64) {
            int idx = b0 + tid;
            int v0 = (idx < NBKT) ? cntL[idx] : 0;
            int v = v0;
            for (int d = 1; d < 64; d <<= 1) {
                int u = __shfl_up(v, d, 64);
                if (tid >= d) v += u;
            }
            if (idx < NBKT) scanB[idx] = carry + v - v0;
            carry += __shfl(v, 63, 64);
        }
    }
    __syncthreads();
#pragma unroll
    for (int j = 0; j < 16; ++j) {
        if (dstr[j] >= 0) {
            int b = dstr[j] >> 8;
            int pos = scanB[b] + atomicAdd(&curL[b], 1);
            sortedD[pos] = descr[j];
            sortedN[pos] = dstr[j];
        }
    }
    for (int i = tid; i < NBKT; i += 256)
        if (cntL[i] > 0) gbaseL[i] = atomicAdd(&bucketCursor[i], cntL[i]);
    __syncthreads();
    for (int i = tid; i < myCount; i += 256) {
        int n = sortedN[i];
        int b = n >> 8;
        int2 pr; pr.x = sortedD[i]; pr.y = n;
        staging[gbaseL[b] + (i - scanB[b])] = pr;
    }
}

// ---------- sort pass 2: per-bucket exact sort + offs ----------
__global__ __launch_bounds__(256) void k_psort2(const int* __restrict__ bucketBase,
                                                const int2* __restrict__ staging,
                                                int* __restrict__ edesc,
                                                int* __restrict__ offs) {
    __shared__ int cnt[256], sbase[256], cur[256];
    int b = blockIdx.x, tid = threadIdx.x;
    int base = bucketBase[b];
    int nb = bucketBase[b + 1] - base;
    cnt[tid] = 0; cur[tid] = 0;
    __syncthreads();
    for (int i = tid; i < nb; i += 256)
        atomicAdd(&cnt[staging[base + i].y & 255], 1);
    __syncthreads();
    int v = cnt[tid];
    sbase[tid] = v;
    __syncthreads();
    for (int d = 1; d < 256; d <<= 1) {
        int u = (tid >= d) ? sbase[tid - d] : 0;
        __syncthreads();
        sbase[tid] += u;
        __syncthreads();
    }
    int ex = sbase[tid] - v;
    int dst = (b << 8) + tid;
    if (dst < N_NODES) offs[dst] = base + ex;
    sbase[tid] = ex;
    __syncthreads();
    for (int i = tid; i < nb; i += 256) {
        int2 pr = staging[base + i];
        int local = pr.y & 255;
        int pos = base + sbase[local] + atomicAdd(&cur[local], 1);
        edesc[pos] = pr.x;
    }
}

// T = R(d) @ W_e + bias (pre-scaled by log2e); tail blocks do weight prep
__global__ __launch_bounds__(256) void k_table2(const float* __restrict__ Wf,
                                                const float* __restrict__ bf,
                                                const float* __restrict__ Ws,
                                                const float* __restrict__ bs,
                                                const float* __restrict__ We,
                                                unsigned int* __restrict__ Tp,
                                                unsigned int* __restrict__ Bp,
                                                unsigned int* __restrict__ BpE) {
    int tid = threadIdx.x;
    int l = blockIdx.y;
    if (blockIdx.x == 161) {  // node-part weight prep for layer l
        int m = tid >> 6, c = tid & 63;
        const float* Wb = ((m & 2) ? Ws : Wf) + (size_t)l * ZD * ATOM + (m & 1) * ATOM * ATOM + c;
        unsigned int* dst = Bp + (size_t)l * 8192 + (size_t)tid * 32;
        for (int kp = 0; kp < 32; ++kp) {
            float w0 = Wb[(2 * kp) * ATOM] * LOG2E;
            float w1 = Wb[(2 * kp + 1) * ATOM] * LOG2E;
            dst[kp] = pk_bf16(w0, w1);
        }
        return;
    }
    if (blockIdx.x == 162) {  // embed weight prep (once)
        if (l != 0) return;
        int n = tid & 63, q = tid >> 6;
        for (int kp = q * 16; kp < q * 16 + 16; ++kp) {
            int k0 = 2 * kp, k1 = 2 * kp + 1;
            float w0 = (k0 < ORIG) ? We[k0 * ATOM + n] : 0.f;
            float w1 = (k1 < ORIG) ? We[k1 * ATOM + n] : 0.f;
            BpE[(size_t)n * 64 + kp] = pk_bf16(w0, w1);
        }
        return;
    }
    __shared__ float Wc[NBR * 64], Wsc[NBR * 64], R[32 * NBR];
    int b0 = blockIdx.x * 32;
    const float* srcf = Wf + (size_t)l * ZD * ATOM + 2 * ATOM * ATOM;
    const float* srcs = Ws + (size_t)l * ZD * ATOM + 2 * ATOM * ATOM;
    for (int i = tid; i < NBR * 64; i += 256) {
        Wc[i] = srcf[i] * LOG2E;
        Wsc[i] = srcs[i] * LOG2E;
    }
    for (int i = tid; i < 32 * NBR; i += 256) {
        int bin = i / NBR, k = i - bin * NBR;
        float d = (b0 + bin) * (TMAX / TBINS);
        float diff = d - 0.2f * k;
        R[i] = expf(-5.0f * diff * diff);
    }
    __syncthreads();
    int c = tid & 63;
    float afb = bf[l * ATOM + c] * LOG2E, asb = bs[l * ATOM + c] * LOG2E;
#pragma unroll
    for (int it = 0; it < 8; ++it) {
        int bin = (tid >> 6) + 4 * it;
        int gb = b0 + bin;
        if (gb <= TBINS) {
            float af = afb, as = asb;
            for (int k = 0; k < NBR; ++k) {
                float r = R[bin * NBR + k];
                af += r * Wc[k * 64 + c];
                as += r * Wsc[k * 64 + c];
            }
            Tp[(size_t)l * TS + (size_t)gb * 64 + c] = pk_bf16(af, as);
        }
    }
}

// fused: embed MFMA (K=128) -> h, then layer-0 projection MFMA -> Pi, Pj
__global__ __launch_bounds__(256) void k_embed_nodeP(const float* __restrict__ x,
                                                     const unsigned int* __restrict__ BpE,
                                                     const float* __restrict__ be,
                                                     const unsigned int* __restrict__ Bp,
                                                     float* __restrict__ h,
                                                     unsigned int* __restrict__ Pi,
                                                     unsigned int* __restrict__ Pj) {
    __shared__ char smem[46080];
    short* Ae = (short*)smem;              // [64][SPE]
    short* Be = (short*)(smem + 17408);    // [64][SPE]
    short* Bn = (short*)smem;              // [256][SP]  aliases Ae/Be (after sync)
    short* An = (short*)(smem + 36864);    // [64][SP]
    int tid = threadIdx.x;
    int n0 = blockIdx.x * 64;
    for (int i = tid; i < 64 * 64; i += 256) {
        int r = i >> 6, kp = i & 63;
        int node = n0 + r;
        float2 v = make_float2(0.f, 0.f);
        if (node < N_NODES && kp < 46) v = ((const float2*)x)[(size_t)node * 46 + kp];
        *(unsigned int*)&Ae[r * SPE + kp * 2] = pk_bf16(v.x, v.y);
    }
    {
        const uint4* src = (const uint4*)BpE;
        for (int i = tid; i < 64 * 16; i += 256) {
            int row = i >> 4, q = i & 15;
            *(uint4*)&Be[row * SPE + q * 8] = src[i];
        }
    }
    __syncthreads();
    int lane = tid & 63, w = tid >> 6;
    int c15 = lane & 15, kb = lane >> 4;
    {
        short8 af[4];
#pragma unroll
        for (int s = 0; s < 4; ++s)
            af[s] = *(const short8*)&Ae[(16 * w + c15) * SPE + s * 32 + kb * 8];
        f32x4 acc[4];
#pragma unroll
        for (int t = 0; t < 4; ++t) acc[t] = (f32x4){0.f, 0.f, 0.f, 0.f};
#pragma unroll
        for (int t = 0; t < 4; ++t) {
#pragma unroll
            for (int s = 0; s < 4; ++s) {
                short8 bf8 = *(const short8*)&Be[(16 * t + c15) * SPE + s * 32 + kb * 8];
                acc[t] = __builtin_amdgcn_mfma_f32_16x16x32_bf16(af[s], bf8, acc[t], 0, 0, 0);
            }
        }
#pragma unroll
        for (int t = 0; t < 4; ++t) {
            float bias = be[16 * t + c15];
#pragma unroll
            for (int reg = 0; reg < 4; ++reg) {
                int row = 16 * w + kb * 4 + reg;
                int node = n0 + row;
                float v = acc[t][reg] + bias;
                if (node < N_NODES) h[(size_t)node * 64 + 16 * t + c15] = v;
                An[row * SP + 16 * t + c15] = (short)pk_bf16(v, v);
            }
        }
    }
    __syncthreads();
    {
        const uint4* src = (const uint4*)Bp;   // layer 0
        for (int i = tid; i < 2048; i += 256) {
            int row = i >> 3, j = i & 7;
            *(uint4*)&Bn[row * SP + j * 8] = src[row * 8 + j];
        }
    }
    __syncthreads();
    short8 af2[2];
#pragma unroll
    for (int s = 0; s < 2; ++s)
        af2[s] = *(const short8*)&An[(16 * w + c15) * SP + s * 32 + kb * 8];
    f32x4 acc2[16];
#pragma unroll
    for (int t = 0; t < 16; ++t) acc2[t] = (f32x4){0.f, 0.f, 0.f, 0.f};
#pragma unroll
    for (int t = 0; t < 16; ++t) {
#pragma unroll
        for (int s = 0; s < 2; ++s) {
            short8 bf8 = *(const short8*)&Bn[(16 * t + c15) * SP + s * 32 + kb * 8];
            acc2[t] = __builtin_amdgcn_mfma_f32_16x16x32_bf16(af2[s], bf8, acc2[t], 0, 0, 0);
        }
    }
#pragma unroll
    for (int t = 0; t < 4; ++t) {
#pragma unroll
        for (int reg = 0; reg < 4; ++reg) {
            int row = kb * 4 + reg;
            int node = n0 + 16 * w + row;
            if (node < N_NODES) {
                Pi[(size_t)node * 64 + 16 * t + c15] = pk_bf16(acc2[t][reg], acc2[t + 8][reg]);
                Pj[(size_t)node * 64 + 16 * t + c15] = pk_bf16(acc2[t + 4][reg], acc2[t + 12][reg]);
            }
        }
    }
}

// fused: BN+residual update of h, then MFMA projection -> Pi, Pj (layers 1,2)
__global__ __launch_bounds__(256) void k_nodeP_mfma(float* __restrict__ h,
                                                    const float* __restrict__ agg,
                                                    const float* __restrict__ ss,
                                                    const unsigned int* __restrict__ Bp,
                                                    int l,
                                                    unsigned int* __restrict__ Pi,
                                                    unsigned int* __restrict__ Pj) {
    __shared__ short A[64 * SP];
    __shared__ short B[256 * SP];
    int tid = threadIdx.x;
    int n0 = blockIdx.x * 64;
    for (int i = tid; i < 64 * 16; i += 256) {
        int r = i >> 4, kq = i & 15;
        int node = n0 + r;
        float4 hv = make_float4(0.f, 0.f, 0.f, 0.f);
        if (node < N_NODES) {
            hv = ((const float4*)h)[(size_t)node * 16 + kq];
            float4 av = ((const float4*)agg)[(size_t)node * 16 + kq];
            int c = kq * 4;
            hv.x = sp_fast2(ss[c] * av.x + ss[64 + c] + hv.x);
            hv.y = sp_fast2(ss[c + 1] * av.y + ss[64 + c + 1] + hv.y);
            hv.z = sp_fast2(ss[c + 2] * av.z + ss[64 + c + 2] + hv.z);
            hv.w = sp_fast2(ss[c + 3] * av.w + ss[64 + c + 3] + hv.w);
            ((float4*)h)[(size_t)node * 16 + kq] = hv;
        }
        uint2 pk2;
        pk2.x = pk_bf16(hv.x, hv.y);
        pk2.y = pk_bf16(hv.z, hv.w);
        *(uint2*)&A[r * SP + kq * 4] = pk2;
    }
    {
        const uint4* src = (const uint4*)(Bp + (size_t)l * 8192);
        for (int i = tid; i < 2048; i += 256) {
            int row = i >> 3, j = i & 7;
            *(uint4*)&B[row * SP + j * 8] = src[row * 8 + j];
        }
    }
    __syncthreads();
    int lane = tid & 63, w = tid >> 6;
    int c15 = lane & 15, kb = lane >> 4;
    short8 af[2];
#pragma unroll
    for (int s = 0; s < 2; ++s)
        af[s] = *(const short8*)&A[(16 * w + c15) * SP + s * 32 + kb * 8];
    f32x4 acc[16];
#pragma unroll
    for (int t = 0; t < 16; ++t) acc[t] = (f32x4){0.f, 0.f, 0.f, 0.f};
#pragma unroll
    for (int t = 0; t < 16; ++t) {
#pragma unroll
        for (int s = 0; s < 2; ++s) {
            short8 bf8 = *(const short8*)&B[(16 * t + c15) * SP + s * 32 + kb * 8];
            acc[t] = __builtin_amdgcn_mfma_f32_16x16x32_bf16(af[s], bf8, acc[t], 0, 0, 0);
        }
    }
#pragma unroll
    for (int t = 0; t < 4; ++t) {
#pragma unroll
        for (int reg = 0; reg < 4; ++reg) {
            int row = kb * 4 + reg;
            int node = n0 + 16 * w + row;
            if (node < N_NODES) {
                Pi[(size_t)node * 64 + 16 * t + c15] = pk_bf16(acc[t][reg], acc[t + 8][reg]);
                Pj[(size_t)node * 64 + 16 * t + c15] = pk_bf16(acc[t + 4][reg], acc[t + 12][reg]);
            }
        }
    }
}

// one wave per node (exact grid); packed-f32 gate/core math; fused BN-stats epilogue
__global__ __launch_bounds__(256, 4) void k_edge_sorted(const int* __restrict__ offs,
                                                        const int* __restrict__ edesc,
                                                        const unsigned int* __restrict__ Pi,
                                                        const unsigned int* __restrict__ Pj,
                                                        const unsigned int* __restrict__ Tp,
                                                        float* __restrict__ agg,
                                                        float* __restrict__ pstats) {
    __shared__ float es[4][64], es2[4][64];
    int wid = (blockIdx.x * 256 + threadIdx.x) >> 6;
    int lane = threadIdx.x & 63;
    int w = threadIdx.x >> 6;
    int uwid = __builtin_amdgcn_readfirstlane(wid);
    int2 kk;
    asm volatile("s_load_dwordx2 %0, %1, 0x0\n\ts_waitcnt lgkmcnt(0)"
                 : "=s"(kk) : "s"(offs + uwid));
    int ko = kk.x, ke = kk.y;
    unsigned int pi = Pi[(size_t)uwid * 64 + lane];
    f32x2 gic;
    gic.x = bf_lo(pi);
    gic.y = bf_hi(pi);
    float acc = 0.0f;
    int lane4 = lane * 4;
    const char* PjB = (const char*)Pj;
    const char* TpB = (const char*)Tp;
    int k0 = ko;
    for (; k0 + 16 <= ke; k0 += 16) {
        int8v e0, e1;
        asm volatile(
            "s_load_dwordx8 %0, %2, 0x0\n\t"
            "s_load_dwordx8 %1, %2, 0x20\n\t"
            "s_waitcnt lgkmcnt(0)"
            : "=&s"(e0), "=&s"(e1)
            : "s"(edesc + k0));
        unsigned int pjv[16], tjv[16];
#pragma unroll
        for (int j = 0; j < 16; ++j) {
            int v = (j < 8) ? e0[j & 7] : e1[j & 7];
            int sb = (v & 0x1FFFF) << 8;
            int tb = (v >> 17) << 8;
            pjv[j] = *(const unsigned int*)(PjB + sb + lane4);
            tjv[j] = *(const unsigned int*)(TpB + tb + lane4);
        }
#pragma unroll
        for (int j = 0; j < 16; ++j) {
            f32x2 a, b;
            a.x = bf_lo(pjv[j]); a.y = bf_hi(pjv[j]);
            b.x = bf_lo(tjv[j]); b.y = bf_hi(tjv[j]);
            f32x2 gc = pk_addf(pk_addf(a, b), gic);
            float sg = __builtin_amdgcn_rcpf(1.0f + __builtin_amdgcn_exp2f(-gc.x));
            float sp = fmaxf(gc.y, 0.0f) + __builtin_amdgcn_logf(1.0f + __builtin_amdgcn_exp2f(-fabsf(gc.y)));
            acc = fmaf(sg, sp, acc);
        }
    }
    if (k0 < ke) {
        int8v e0, e1;
        asm volatile(
            "s_load_dwordx8 %0, %2, 0x0\n\t"
            "s_load_dwordx8 %1, %2, 0x20\n\t"
            "s_waitcnt lgkmcnt(0)"
            : "=&s"(e0), "=&s"(e1)
            : "s"(edesc + k0));
        unsigned int pjv[16], tjv[16];
#pragma unroll
        for (int j = 0; j < 16; ++j) {
            if (k0 + j < ke) {
                int v = (j < 8) ? e0[j & 7] : e1[j & 7];
                int sb = (v & 0x1FFFF) << 8;
                int tb = (v >> 17) << 8;
                pjv[j] = *(const unsigned int*)(PjB + sb + lane4);
                tjv[j] = *(const unsigned int*)(TpB + tb + lane4);
            }
        }
#pragma unroll
        for (int j = 0; j < 16; ++j) {
            if (k0 + j < ke) {
                f32x2 a, b;
                a.x = bf_lo(pjv[j]); a.y = bf_hi(pjv[j]);
                b.x = bf_lo(tjv[j]); b.y = bf_hi(tjv[j]);
                f32x2 gc = pk_addf(pk_addf(a, b), gic);
                float sg = __builtin_amdgcn_rcpf(1.0f + __builtin_amdgcn_exp2f(-gc.x));
                float sp = fmaxf(gc.y, 0.0f) + __builtin_amdgcn_logf(1.0f + __builtin_amdgcn_exp2f(-fabsf(gc.y)));
                acc = fmaf(sg, sp, acc);
            }
        }
    }
    agg[(size_t)uwid * 64 + lane] = acc;   // un-scaled; BN compensates via EPS2
    es[w][lane] = acc;
    es2[w][lane] = acc * acc;
    __syncthreads();
    if (threadIdx.x < 64) {
        float s = es[0][threadIdx.x] + es[1][threadIdx.x] + es[2][threadIdx.x] + es[3][threadIdx.x];
        float s2 = es2[0][threadIdx.x] + es2[1][threadIdx.x] + es2[2][threadIdx.x] + es2[3][threadIdx.x];
        float* slot = pstats + (size_t)(blockIdx.x & (PSLOT - 1)) * 128;
        atomicAdd(&slot[threadIdx.x], s);
        atomicAdd(&slot[64 + threadIdx.x], s2);
    }
}

// reduce pstats -> ss, then re-zero pstats for the next layer
__global__ __launch_bounds__(128) void k_bnfinal(float* __restrict__ pstats,
                                                 const float* __restrict__ gamma,
                                                 const float* __restrict__ beta,
                                                 int l, float* __restrict__ ss) {
    __shared__ float ls[128];
    int t = threadIdx.x;
    float sum = 0.0f;
    for (int b = 0; b < PSLOT; ++b) sum += pstats[b * 128 + t];
    ls[t] = sum;
    for (int b = t; b < PSLOT * 128; b += 128) pstats[b] = 0.0f;
    __syncthreads();
    if (t < 64) {
        const float inv = 1.0f / (float)N_NODES;
        float mu = ls[t] * inv;
        float var = ls[64 + t] * inv - mu * mu;
        float sc = gamma[l * ATOM + t] * rsqrtf(var + EPS2);
        ss[t] = sc;
        ss[64 + t] = beta[l * ATOM + t] - mu * sc;
    }
}

// fused final update + pool; batch is sorted -> run-length accumulate
__global__ __launch_bounds__(256) void k_pool2(const float* __restrict__ agg,
                                               const float* __restrict__ ss,
                                               const float* __restrict__ h,
                                               const int* __restrict__ batch,
                                               float* __restrict__ g) {
    int w = threadIdx.x >> 6, lane = threadIdx.x & 63;
    int nbase = blockIdx.x * 64 + w * 16;
    float acc = 0.0f;
    int curg = -1;
    float sc = ss[lane], sh = ss[64 + lane];
    for (int i = 0; i < 16; ++i) {
        int n = nbase + i;
        if (n >= N_NODES) break;
        int gid = __builtin_amdgcn_readfirstlane(batch[n]);
        if (gid != curg) {
            if (curg >= 0) atomicAdd(&g[(size_t)curg * ATOM + lane], acc);
            curg = gid;
            acc = 0.0f;
        }
        float x = sc * agg[(size_t)n * 64 + lane] + sh + h[(size_t)n * 64 + lane];
        acc += sp_fast2(x);
    }
    if (curg >= 0) atomicAdd(&g[(size_t)curg * ATOM + lane], acc);
}

__global__ __launch_bounds__(128) void k_head(const float* __restrict__ g,
                                              const float* __restrict__ W1,
                                              const float* __restrict__ b1,
                                              const float* __restrict__ W2,
                                              const float* __restrict__ b2,
                                              float* __restrict__ out) {
    __shared__ float red[128];
    int gid = blockIdx.x, j = threadIdx.x;
    float acc = b1[j];
    for (int k = 0; k < ATOM; ++k) acc += g[gid * ATOM + k] * W1[k * HFEA + j];
    red[j] = softplus_f(acc) * W2[j];
    __syncthreads();
    for (int s = 64; s > 0; s >>= 1) {
        if (j < s) red[j] += red[j + s];
        __syncthreads();
    }
    if (j == 0) out[gid] = red[0] + b2[0];
}

extern "C" void kernel_launch(void* const* d_in, const int* in_sizes, int n_in,
                              void* d_out, int out_size, void* d_ws, size_t ws_size,
                              hipStream_t stream) {
    const float* x       = (const float*)d_in[0];
    const float* ea      = (const float*)d_in[1];
    const float* W_emb   = (const float*)d_in[2];
    const float* b_emb   = (const float*)d_in[3];
    const float* Wf      = (const float*)d_in[4];
    const float* bf      = (const float*)d_in[5];
    const float* Ws      = (const float*)d_in[6];
    const float* bs      = (const float*)d_in[7];
    const float* bn_g    = (const float*)d_in[8];
    const float* bn_b    = (const float*)d_in[9];
    const float* W1      = (const float*)d_in[10];
    const float* b1      = (const float*)d_in[11];
    const float* W2      = (const float*)d_in[12];
    const float* b2      = (const float*)d_in[13];
    const int*   ei      = (const int*)d_in[14];
    const int*   batch   = (const int*)d_in[15];
    float* out = (float*)d_out;

    char* wsb = (char*)d_ws;
    size_t off = 0;
    auto alloc = [&](size_t bytes) { char* p = wsb + off; off += (bytes + 255) & ~(size_t)255; return p; };
    float*        h        = (float*)alloc((size_t)N_NODES * 64 * 4);
    float*        agg      = (float*)alloc((size_t)N_NODES * 64 * 4);
    unsigned int* Pi       = (unsigned int*)alloc((size_t)N_NODES * 64 * 4);
    unsigned int* Pj       = (unsigned int*)alloc((size_t)N_NODES * 64 * 4);
    int*          edesc    = (int*)alloc((size_t)(N_EDGES + 16) * 4);
    int2*         staging  = (int2*)alloc((size_t)N_EDGES * 8);
    int*          meta     = (int*)alloc((1024 + PSLOT * 128) * 4);
    int*          bucketCnt    = meta;
    int*          flag         = meta + 512;
    float*        pstats       = (float*)(meta + 1024);
    int*          bucketBase   = (int*)alloc(520 * 4);
    int*          bucketCursor = (int*)alloc(512 * 4);
    int*          offs     = (int*)alloc((size_t)(N_NODES + 1) * 4);
    unsigned int* Tp       = (unsigned int*)alloc((size_t)NCONV * TS * 4);
    unsigned int* Bp       = (unsigned int*)alloc((size_t)NCONV * 8192 * 4);
    unsigned int* BpE      = (unsigned int*)alloc((size_t)64 * 64 * 4);
    float*        ss       = (float*)alloc(128 * 4);
    float*        g        = (float*)alloc((size_t)NGRAPH * 64 * 4);

    (void)hipMemsetAsync(meta, 0, (1024 + PSLOT * 128) * 4, stream);
    k_bhist<<<256, 256, 0, stream>>>(ei, bucketCnt, flag, bucketBase, bucketCursor, offs);
    k_psort1<<<(N_EDGES + S3CH - 1) / S3CH, 256, 0, stream>>>(ei, ea, bucketCursor, staging);
    k_psort2<<<NBKT, 256, 0, stream>>>(bucketBase, staging, edesc, offs);

    dim3 tg(163, NCONV);
    k_table2<<<tg, 256, 0, stream>>>(Wf, bf, Ws, bs, W_emb, Tp, Bp, BpE);
    k_embed_nodeP<<<(N_NODES + 63) / 64, 256, 0, stream>>>(x, BpE, b_emb, Bp, h, Pi, Pj);

    for (int l = 0; l < NCONV; ++l) {
        if (l > 0)
            k_nodeP_mfma<<<(N_NODES + 63) / 64, 256, 0, stream>>>(h, agg, ss, Bp, l, Pi, Pj);
        k_edge_sorted<<<N_NODES * 64 / 256, 256, 0, stream>>>(
            offs, edesc, Pi, Pj, Tp + (size_t)l * TS, agg, pstats);
        k_bnfinal<<<1, 128, 0, stream>>>(pstats, bn_g, bn_b, l, ss);
    }

    (void)hipMemsetAsync(g, 0, (size_t)NGRAPH * 64 * 4, stream);
    k_pool2<<<(N_NODES + 63) / 64, 256, 0, stream>>>(agg, ss, h, batch, g);
    k_head<<<NGRAPH, 128, 0, stream>>>(g, W1, b1, W2, b2, out);
}

// Round 17
// 404.454 us; speedup vs baseline: 1.0355x; 1.0355x over previous
//
#include <hip/hip_runtime.h>
#include <hip/hip_bf16.h>
#include <math.h>

#define N_NODES 100000
#define N_EDGES 1600000
#define ORIG    92
#define NBR     41
#define ATOM    64
#define NCONV   3
#define HFEA    128
#define NGRAPH  256
#define ZD      169           // 2*ATOM + NBR
#define TBINS   5120
#define TMAX    10.0f
#define TS      ((TBINS + 1) * 64)   // per-layer table stride (uints)
#define SP      72                   // nodeP LDS row pad (shorts)
#define SPE     136                  // embed LDS row pad (shorts), K=128
#define LOG2E   1.4426950408889634f
#define LN2     0.6931471805599453f
#define EPS2    (1e-5f / (LN2 * LN2))   // BN eps compensated for un-scaled agg
#define NBKT    391                  // ceil(N_NODES / 256)
#define S1E     6250                 // edges per k_bhist block (256 blocks exact)
#define S3CH    4096                 // edges per k_psort1 block
#define PSLOT   128                  // pstats slots

typedef __attribute__((ext_vector_type(8))) short short8;
typedef __attribute__((ext_vector_type(4))) float f32x4;
typedef __attribute__((ext_vector_type(8))) int int8v;

__device__ __forceinline__ float softplus_f(float x) {
    return fmaxf(x, 0.0f) + log1pf(expf(-fabsf(x)));
}
// fast softplus via exp2/log2 HW ops
__device__ __forceinline__ float sp_fast2(float x) {
    float t = x * LOG2E;
    return LN2 * (fmaxf(t, 0.0f) +
                  __builtin_amdgcn_logf(1.0f + __builtin_amdgcn_exp2f(-fabsf(t))));
}
// pack 2 fp32 -> 2 bf16 in one uint
__device__ __forceinline__ unsigned int pk_bf16(float lo, float hi) {
    unsigned int r;
    asm("v_cvt_pk_bf16_f32 %0, %1, %2" : "=v"(r) : "v"(lo), "v"(hi));
    return r;
}
__device__ __forceinline__ float bf_lo(unsigned int p) { return __uint_as_float(p << 16); }
__device__ __forceinline__ float bf_hi(unsigned int p) { return __uint_as_float(p & 0xffff0000u); }

// ---------- sort pass 0: coarse bucket histogram + last-block scan ----------
__global__ __launch_bounds__(256) void k_bhist(const int* __restrict__ ei,
                                               int* __restrict__ bucketCnt,
                                               int* __restrict__ flag,
                                               int* __restrict__ bucketBase,
                                               int* __restrict__ bucketCursor,
                                               int* __restrict__ offs) {
    __shared__ int cntL[NBKT];
    __shared__ int lastFlag;
    int tid = threadIdx.x;
    for (int i = tid; i < NBKT; i += 256) cntL[i] = 0;
    __syncthreads();
    int base = blockIdx.x * S1E;
    for (int i = tid; i < S1E; i += 256)
        atomicAdd(&cntL[ei[N_EDGES + base + i] >> 8], 1);
    __syncthreads();
    for (int i = tid; i < NBKT; i += 256)
        if (cntL[i]) atomicAdd(&bucketCnt[i], cntL[i]);
    if (tid == 0) {
        __threadfence();
        lastFlag = (atomicAdd(flag, 1) == 255) ? 1 : 0;
    }
    __syncthreads();
    if (lastFlag && tid < 64) {
        __threadfence();
        int carry = 0;
        for (int b0 = 0; b0 < NBKT; b0 += 64) {
            int idx = b0 + tid;
            int v0 = (idx < NBKT) ? bucketCnt[idx] : 0;
            int v = v0;
            for (int d = 1; d < 64; d <<= 1) {
                int u = __shfl_up(v, d, 64);
                if (tid >= d) v += u;
            }
            if (idx < NBKT) {
                int ex = carry + v - v0;
                bucketBase[idx] = ex;
                bucketCursor[idx] = ex;
            }
            carry += __shfl(v, 63, 64);
        }
        if (tid == 0) {
            bucketBase[NBKT] = N_EDGES;
            offs[N_NODES] = N_EDGES;
        }
    }
}

// ---------- sort pass 1: bucket-binned staging, coalesced burst writes ----------
__global__ __launch_bounds__(256) void k_psort1(const int* __restrict__ ei,
                                                const float* __restrict__ ea,
                                                int* __restrict__ bucketCursor,
                                                int2* __restrict__ staging) {
    __shared__ int cntL[NBKT], scanB[NBKT], curL[NBKT], gbaseL[NBKT];
    __shared__ int sortedD[S3CH], sortedN[S3CH];
    int tid = threadIdx.x;
    int base = blockIdx.x * S3CH;
    int myCount = N_EDGES - base;
    if (myCount > S3CH) myCount = S3CH;
    for (int i = tid; i < NBKT; i += 256) { cntL[i] = 0; curL[i] = 0; }
    __syncthreads();
    int descr[16], dstr[16];
#pragma unroll
    for (int j = 0; j < 16; ++j) {
        int i = j * 256 + tid;
        descr[j] = 0; dstr[j] = -1;
        if (i < myCount) {
            int e = base + i;
            int src = ei[e];
            int dst = ei[N_EDGES + e];
            float a = ea[3 * e], bb = ea[3 * e + 1], c = ea[3 * e + 2];
            float d = sqrtf(a * a + bb * bb + c * c);
            int bin = (int)fminf(fmaf(d, (float)TBINS / TMAX, 0.5f), (float)TBINS);
            descr[j] = (bin << 17) | src;
            dstr[j] = dst;
            atomicAdd(&cntL[dst >> 8], 1);
        }
    }
    __syncthreads();
    if (tid < 64) {  // wave 0 exclusive-scans cntL
        int carry = 0;
        for (int b0 = 0; b0 < NBKT; b0 += 64) {
            int idx = b0 + tid;
            int v0 = (idx < NBKT) ? cntL[idx] : 0;
            int v = v0;
            for (int d = 1; d < 64; d <<= 1) {
                int u = __shfl_up(v, d, 64);
                if (tid >= d) v += u;
            }
            if (idx < NBKT) scanB[idx] = carry + v - v0;
            carry += __shfl(v, 63, 64);
        }
    }
    __syncthreads();
#pragma unroll
    for (int j = 0; j < 16; ++j) {
        if (dstr[j] >= 0) {
            int b = dstr[j] >> 8;
            int pos = scanB[b] + atomicAdd(&curL[b], 1);
            sortedD[pos] = descr[j];
            sortedN[pos] = dstr[j];
        }
    }
    for (int i = tid; i < NBKT; i += 256)
        if (cntL[i] > 0) gbaseL[i] = atomicAdd(&bucketCursor[i], cntL[i]);
    __syncthreads();
    for (int i = tid; i < myCount; i += 256) {
        int n = sortedN[i];
        int b = n >> 8;
        int2 pr; pr.x = sortedD[i]; pr.y = n;
        staging[gbaseL[b] + (i - scanB[b])] = pr;
    }
}

// ---------- sort pass 2: per-bucket exact sort + offs ----------
__global__ __launch_bounds__(256) void k_psort2(const int* __restrict__ bucketBase,
                                                const int2* __restrict__ staging,
                                                int* __restrict__ edesc,
                                                int* __restrict__ offs) {
    __shared__ int cnt[256], sbase[256], cur[256];
    int b = blockIdx.x, tid = threadIdx.x;
    int base = bucketBase[b];
    int nb = bucketBase[b + 1] - base;
    cnt[tid] = 0; cur[tid] = 0;
    __syncthreads();
    for (int i = tid; i < nb; i += 256)
        atomicAdd(&cnt[staging[base + i].y & 255], 1);
    __syncthreads();
    int v = cnt[tid];
    sbase[tid] = v;
    __syncthreads();
    for (int d = 1; d < 256; d <<= 1) {
        int u = (tid >= d) ? sbase[tid - d] : 0;
        __syncthreads();
        sbase[tid] += u;
        __syncthreads();
    }
    int ex = sbase[tid] - v;
    int dst = (b << 8) + tid;
    if (dst < N_NODES) offs[dst] = base + ex;
    sbase[tid] = ex;
    __syncthreads();
    for (int i = tid; i < nb; i += 256) {
        int2 pr = staging[base + i];
        int local = pr.y & 255;
        int pos = base + sbase[local] + atomicAdd(&cur[local], 1);
        edesc[pos] = pr.x;
    }
}

// T = R(d) @ W_e + bias (pre-scaled by log2e); tail blocks do weight prep
__global__ __launch_bounds__(256) void k_table2(const float* __restrict__ Wf,
                                                const float* __restrict__ bf,
                                                const float* __restrict__ Ws,
                                                const float* __restrict__ bs,
                                                const float* __restrict__ We,
                                                unsigned int* __restrict__ Tp,
                                                unsigned int* __restrict__ Bp,
                                                unsigned int* __restrict__ BpE) {
    int tid = threadIdx.x;
    int l = blockIdx.y;
    if (blockIdx.x == 161) {  // node-part weight prep for layer l
        int m = tid >> 6, c = tid & 63;
        const float* Wb = ((m & 2) ? Ws : Wf) + (size_t)l * ZD * ATOM + (m & 1) * ATOM * ATOM + c;
        unsigned int* dst = Bp + (size_t)l * 8192 + (size_t)tid * 32;
        for (int kp = 0; kp < 32; ++kp) {
            float w0 = Wb[(2 * kp) * ATOM] * LOG2E;
            float w1 = Wb[(2 * kp + 1) * ATOM] * LOG2E;
            dst[kp] = pk_bf16(w0, w1);
        }
        return;
    }
    if (blockIdx.x == 162) {  // embed weight prep (once)
        if (l != 0) return;
        int n = tid & 63, q = tid >> 6;
        for (int kp = q * 16; kp < q * 16 + 16; ++kp) {
            int k0 = 2 * kp, k1 = 2 * kp + 1;
            float w0 = (k0 < ORIG) ? We[k0 * ATOM + n] : 0.f;
            float w1 = (k1 < ORIG) ? We[k1 * ATOM + n] : 0.f;
            BpE[(size_t)n * 64 + kp] = pk_bf16(w0, w1);
        }
        return;
    }
    __shared__ float Wc[NBR * 64], Wsc[NBR * 64], R[32 * NBR];
    int b0 = blockIdx.x * 32;
    const float* srcf = Wf + (size_t)l * ZD * ATOM + 2 * ATOM * ATOM;
    const float* srcs = Ws + (size_t)l * ZD * ATOM + 2 * ATOM * ATOM;
    for (int i = tid; i < NBR * 64; i += 256) {
        Wc[i] = srcf[i] * LOG2E;
        Wsc[i] = srcs[i] * LOG2E;
    }
    for (int i = tid; i < 32 * NBR; i += 256) {
        int bin = i / NBR, k = i - bin * NBR;
        float d = (b0 + bin) * (TMAX / TBINS);
        float diff = d - 0.2f * k;
        R[i] = expf(-5.0f * diff * diff);
    }
    __syncthreads();
    int c = tid & 63;
    float afb = bf[l * ATOM + c] * LOG2E, asb = bs[l * ATOM + c] * LOG2E;
#pragma unroll
    for (int it = 0; it < 8; ++it) {
        int bin = (tid >> 6) + 4 * it;
        int gb = b0 + bin;
        if (gb <= TBINS) {
            float af = afb, as = asb;
            for (int k = 0; k < NBR; ++k) {
                float r = R[bin * NBR + k];
                af += r * Wc[k * 64 + c];
                as += r * Wsc[k * 64 + c];
            }
            Tp[(size_t)l * TS + (size_t)gb * 64 + c] = pk_bf16(af, as);
        }
    }
}

// fused: embed MFMA (K=128) -> h, then layer-0 projection MFMA -> Pi, Pj
__global__ __launch_bounds__(256) void k_embed_nodeP(const float* __restrict__ x,
                                                     const unsigned int* __restrict__ BpE,
                                                     const float* __restrict__ be,
                                                     const unsigned int* __restrict__ Bp,
                                                     float* __restrict__ h,
                                                     unsigned int* __restrict__ Pi,
                                                     unsigned int* __restrict__ Pj) {
    __shared__ char smem[46080];
    short* Ae = (short*)smem;              // [64][SPE]
    short* Be = (short*)(smem + 17408);    // [64][SPE]
    short* Bn = (short*)smem;              // [256][SP]  aliases Ae/Be (after sync)
    short* An = (short*)(smem + 36864);    // [64][SP]
    int tid = threadIdx.x;
    int n0 = blockIdx.x * 64;
    for (int i = tid; i < 64 * 64; i += 256) {
        int r = i >> 6, kp = i & 63;
        int node = n0 + r;
        float2 v = make_float2(0.f, 0.f);
        if (node < N_NODES && kp < 46) v = ((const float2*)x)[(size_t)node * 46 + kp];
        *(unsigned int*)&Ae[r * SPE + kp * 2] = pk_bf16(v.x, v.y);
    }
    {
        const uint4* src = (const uint4*)BpE;
        for (int i = tid; i < 64 * 16; i += 256) {
            int row = i >> 4, q = i & 15;
            *(uint4*)&Be[row * SPE + q * 8] = src[i];
        }
    }
    __syncthreads();
    int lane = tid & 63, w = tid >> 6;
    int c15 = lane & 15, kb = lane >> 4;
    {
        short8 af[4];
#pragma unroll
        for (int s = 0; s < 4; ++s)
            af[s] = *(const short8*)&Ae[(16 * w + c15) * SPE + s * 32 + kb * 8];
        f32x4 acc[4];
#pragma unroll
        for (int t = 0; t < 4; ++t) acc[t] = (f32x4){0.f, 0.f, 0.f, 0.f};
#pragma unroll
        for (int t = 0; t < 4; ++t) {
#pragma unroll
            for (int s = 0; s < 4; ++s) {
                short8 bf8 = *(const short8*)&Be[(16 * t + c15) * SPE + s * 32 + kb * 8];
                acc[t] = __builtin_amdgcn_mfma_f32_16x16x32_bf16(af[s], bf8, acc[t], 0, 0, 0);
            }
        }
#pragma unroll
        for (int t = 0; t < 4; ++t) {
            float bias = be[16 * t + c15];
#pragma unroll
            for (int reg = 0; reg < 4; ++reg) {
                int row = 16 * w + kb * 4 + reg;
                int node = n0 + row;
                float v = acc[t][reg] + bias;
                if (node < N_NODES) h[(size_t)node * 64 + 16 * t + c15] = v;
                An[row * SP + 16 * t + c15] = (short)pk_bf16(v, v);
            }
        }
    }
    __syncthreads();
    {
        const uint4* src = (const uint4*)Bp;   // layer 0
        for (int i = tid; i < 2048; i += 256) {
            int row = i >> 3, j = i & 7;
            *(uint4*)&Bn[row * SP + j * 8] = src[row * 8 + j];
        }
    }
    __syncthreads();
    short8 af2[2];
#pragma unroll
    for (int s = 0; s < 2; ++s)
        af2[s] = *(const short8*)&An[(16 * w + c15) * SP + s * 32 + kb * 8];
    f32x4 acc2[16];
#pragma unroll
    for (int t = 0; t < 16; ++t) acc2[t] = (f32x4){0.f, 0.f, 0.f, 0.f};
#pragma unroll
    for (int t = 0; t < 16; ++t) {
#pragma unroll
        for (int s = 0; s < 2; ++s) {
            short8 bf8 = *(const short8*)&Bn[(16 * t + c15) * SP + s * 32 + kb * 8];
            acc2[t] = __builtin_amdgcn_mfma_f32_16x16x32_bf16(af2[s], bf8, acc2[t], 0, 0, 0);
        }
    }
#pragma unroll
    for (int t = 0; t < 4; ++t) {
#pragma unroll
        for (int reg = 0; reg < 4; ++reg) {
            int row = kb * 4 + reg;
            int node = n0 + 16 * w + row;
            if (node < N_NODES) {
                Pi[(size_t)node * 64 + 16 * t + c15] = pk_bf16(acc2[t][reg], acc2[t + 8][reg]);
                Pj[(size_t)node * 64 + 16 * t + c15] = pk_bf16(acc2[t + 4][reg], acc2[t + 12][reg]);
            }
        }
    }
}

// fused: BN+residual update of h, then MFMA projection -> Pi, Pj (layers 1,2)
__global__ __launch_bounds__(256) void k_nodeP_mfma(float* __restrict__ h,
                                                    const float* __restrict__ agg,
                                                    const float* __restrict__ ss,
                                                    const unsigned int* __restrict__ Bp,
                                                    int l,
                                                    unsigned int* __restrict__ Pi,
                                                    unsigned int* __restrict__ Pj) {
    __shared__ short A[64 * SP];
    __shared__ short B[256 * SP];
    int tid = threadIdx.x;
    int n0 = blockIdx.x * 64;
    for (int i = tid; i < 64 * 16; i += 256) {
        int r = i >> 4, kq = i & 15;
        int node = n0 + r;
        float4 hv = make_float4(0.f, 0.f, 0.f, 0.f);
        if (node < N_NODES) {
            hv = ((const float4*)h)[(size_t)node * 16 + kq];
            float4 av = ((const float4*)agg)[(size_t)node * 16 + kq];
            int c = kq * 4;
            hv.x = sp_fast2(ss[c] * av.x + ss[64 + c] + hv.x);
            hv.y = sp_fast2(ss[c + 1] * av.y + ss[64 + c + 1] + hv.y);
            hv.z = sp_fast2(ss[c + 2] * av.z + ss[64 + c + 2] + hv.z);
            hv.w = sp_fast2(ss[c + 3] * av.w + ss[64 + c + 3] + hv.w);
            ((float4*)h)[(size_t)node * 16 + kq] = hv;
        }
        uint2 pk2;
        pk2.x = pk_bf16(hv.x, hv.y);
        pk2.y = pk_bf16(hv.z, hv.w);
        *(uint2*)&A[r * SP + kq * 4] = pk2;
    }
    {
        const uint4* src = (const uint4*)(Bp + (size_t)l * 8192);
        for (int i = tid; i < 2048; i += 256) {
            int row = i >> 3, j = i & 7;
            *(uint4*)&B[row * SP + j * 8] = src[row * 8 + j];
        }
    }
    __syncthreads();
    int lane = tid & 63, w = tid >> 6;
    int c15 = lane & 15, kb = lane >> 4;
    short8 af[2];
#pragma unroll
    for (int s = 0; s < 2; ++s)
        af[s] = *(const short8*)&A[(16 * w + c15) * SP + s * 32 + kb * 8];
    f32x4 acc[16];
#pragma unroll
    for (int t = 0; t < 16; ++t) acc[t] = (f32x4){0.f, 0.f, 0.f, 0.f};
#pragma unroll
    for (int t = 0; t < 16; ++t) {
#pragma unroll
        for (int s = 0; s < 2; ++s) {
            short8 bf8 = *(const short8*)&B[(16 * t + c15) * SP + s * 32 + kb * 8];
            acc[t] = __builtin_amdgcn_mfma_f32_16x16x32_bf16(af[s], bf8, acc[t], 0, 0, 0);
        }
    }
#pragma unroll
    for (int t = 0; t < 4; ++t) {
#pragma unroll
        for (int reg = 0; reg < 4; ++reg) {
            int row = kb * 4 + reg;
            int node = n0 + 16 * w + row;
            if (node < N_NODES) {
                Pi[(size_t)node * 64 + 16 * t + c15] = pk_bf16(acc[t][reg], acc[t + 8][reg]);
                Pj[(size_t)node * 64 + 16 * t + c15] = pk_bf16(acc[t + 4][reg], acc[t + 12][reg]);
            }
        }
    }
}

// one wave per node (exact grid); scalar gate/core math; fused BN-stats epilogue
__global__ __launch_bounds__(256, 4) void k_edge_sorted(const int* __restrict__ offs,
                                                        const int* __restrict__ edesc,
                                                        const unsigned int* __restrict__ Pi,
                                                        const unsigned int* __restrict__ Pj,
                                                        const unsigned int* __restrict__ Tp,
                                                        float* __restrict__ agg,
                                                        float* __restrict__ pstats) {
    __shared__ float es[4][64], es2[4][64];
    int wid = (blockIdx.x * 256 + threadIdx.x) >> 6;
    int lane = threadIdx.x & 63;
    int w = threadIdx.x >> 6;
    int uwid = __builtin_amdgcn_readfirstlane(wid);
    int2 kk;
    asm volatile("s_load_dwordx2 %0, %1, 0x0\n\ts_waitcnt lgkmcnt(0)"
                 : "=s"(kk) : "s"(offs + uwid));
    int ko = kk.x, ke = kk.y;
    unsigned int pi = Pi[(size_t)uwid * 64 + lane];
    float gi = bf_lo(pi), ci = bf_hi(pi);
    float acc = 0.0f;
    int lane4 = lane * 4;
    const char* PjB = (const char*)Pj;
    const char* TpB = (const char*)Tp;
    int k0 = ko;
    for (; k0 + 16 <= ke; k0 += 16) {
        int8v e0, e1;
        asm volatile(
            "s_load_dwordx8 %0, %2, 0x0\n\t"
            "s_load_dwordx8 %1, %2, 0x20\n\t"
            "s_waitcnt lgkmcnt(0)"
            : "=&s"(e0), "=&s"(e1)
            : "s"(edesc + k0));
        unsigned int pjv[16], tjv[16];
#pragma unroll
        for (int j = 0; j < 16; ++j) {
            int v = (j < 8) ? e0[j & 7] : e1[j & 7];
            int sb = (v & 0x1FFFF) << 8;
            int tb = (v >> 17) << 8;
            pjv[j] = *(const unsigned int*)(PjB + sb + lane4);
            tjv[j] = *(const unsigned int*)(TpB + tb + lane4);
        }
#pragma unroll
        for (int j = 0; j < 16; ++j) {
            float g = gi + bf_lo(pjv[j]) + bf_lo(tjv[j]);
            float c = ci + bf_hi(pjv[j]) + bf_hi(tjv[j]);
            float sg = __builtin_amdgcn_rcpf(1.0f + __builtin_amdgcn_exp2f(-g));
            float sp = fmaxf(c, 0.0f) + __builtin_amdgcn_logf(1.0f + __builtin_amdgcn_exp2f(-fabsf(c)));
            acc = fmaf(sg, sp, acc);
        }
    }
    if (k0 < ke) {
        int8v e0, e1;
        asm volatile(
            "s_load_dwordx8 %0, %2, 0x0\n\t"
            "s_load_dwordx8 %1, %2, 0x20\n\t"
            "s_waitcnt lgkmcnt(0)"
            : "=&s"(e0), "=&s"(e1)
            : "s"(edesc + k0));
        unsigned int pjv[16], tjv[16];
#pragma unroll
        for (int j = 0; j < 16; ++j) {
            if (k0 + j < ke) {
                int v = (j < 8) ? e0[j & 7] : e1[j & 7];
                int sb = (v & 0x1FFFF) << 8;
                int tb = (v >> 17) << 8;
                pjv[j] = *(const unsigned int*)(PjB + sb + lane4);
                tjv[j] = *(const unsigned int*)(TpB + tb + lane4);
            }
        }
#pragma unroll
        for (int j = 0; j < 16; ++j) {
            if (k0 + j < ke) {
                float g = gi + bf_lo(pjv[j]) + bf_lo(tjv[j]);
                float c = ci + bf_hi(pjv[j]) + bf_hi(tjv[j]);
                float sg = __builtin_amdgcn_rcpf(1.0f + __builtin_amdgcn_exp2f(-g));
                float sp = fmaxf(c, 0.0f) + __builtin_amdgcn_logf(1.0f + __builtin_amdgcn_exp2f(-fabsf(c)));
                acc = fmaf(sg, sp, acc);
            }
        }
    }
    agg[(size_t)uwid * 64 + lane] = acc;   // un-scaled; BN compensates via EPS2
    es[w][lane] = acc;
    es2[w][lane] = acc * acc;
    __syncthreads();
    if (threadIdx.x < 64) {
        float s = es[0][threadIdx.x] + es[1][threadIdx.x] + es[2][threadIdx.x] + es[3][threadIdx.x];
        float s2 = es2[0][threadIdx.x] + es2[1][threadIdx.x] + es2[2][threadIdx.x] + es2[3][threadIdx.x];
        float* slot = pstats + (size_t)(blockIdx.x & (PSLOT - 1)) * 128;
        atomicAdd(&slot[threadIdx.x], s);
        atomicAdd(&slot[64 + threadIdx.x], s2);
    }
}

// reduce pstats -> ss, re-zero pstats; on last layer also zero g
__global__ __launch_bounds__(128) void k_bnfinal(float* __restrict__ pstats,
                                                 const float* __restrict__ gamma,
                                                 const float* __restrict__ beta,
                                                 int l, float* __restrict__ ss,
                                                 float* __restrict__ g) {
    __shared__ float ls[128];
    int t = threadIdx.x;
    float sum = 0.0f;
    for (int b = 0; b < PSLOT; ++b) sum += pstats[b * 128 + t];
    ls[t] = sum;
    for (int b = t; b < PSLOT * 128; b += 128) pstats[b] = 0.0f;
    if (l == NCONV - 1)
        for (int i = t; i < NGRAPH * ATOM; i += 128) g[i] = 0.0f;
    __syncthreads();
    if (t < 64) {
        const float inv = 1.0f / (float)N_NODES;
        float mu = ls[t] * inv;
        float var = ls[64 + t] * inv - mu * mu;
        float sc = gamma[l * ATOM + t] * rsqrtf(var + EPS2);
        ss[t] = sc;
        ss[64 + t] = beta[l * ATOM + t] - mu * sc;
    }
}

// fused final update + pool; batch is sorted -> run-length accumulate
__global__ __launch_bounds__(256) void k_pool2(const float* __restrict__ agg,
                                               const float* __restrict__ ss,
                                               const float* __restrict__ h,
                                               const int* __restrict__ batch,
                                               float* __restrict__ g) {
    int w = threadIdx.x >> 6, lane = threadIdx.x & 63;
    int nbase = blockIdx.x * 64 + w * 16;
    float acc = 0.0f;
    int curg = -1;
    float sc = ss[lane], sh = ss[64 + lane];
    for (int i = 0; i < 16; ++i) {
        int n = nbase + i;
        if (n >= N_NODES) break;
        int gid = __builtin_amdgcn_readfirstlane(batch[n]);
        if (gid != curg) {
            if (curg >= 0) atomicAdd(&g[(size_t)curg * ATOM + lane], acc);
            curg = gid;
            acc = 0.0f;
        }
        float x = sc * agg[(size_t)n * 64 + lane] + sh + h[(size_t)n * 64 + lane];
        acc += sp_fast2(x);
    }
    if (curg >= 0) atomicAdd(&g[(size_t)curg * ATOM + lane], acc);
}

__global__ __launch_bounds__(128) void k_head(const float* __restrict__ g,
                                              const float* __restrict__ W1,
                                              const float* __restrict__ b1,
                                              const float* __restrict__ W2,
                                              const float* __restrict__ b2,
                                              float* __restrict__ out) {
    __shared__ float red[128];
    int gid = blockIdx.x, j = threadIdx.x;
    float acc = b1[j];
    for (int k = 0; k < ATOM; ++k) acc += g[gid * ATOM + k] * W1[k * HFEA + j];
    red[j] = softplus_f(acc) * W2[j];
    __syncthreads();
    for (int s = 64; s > 0; s >>= 1) {
        if (j < s) red[j] += red[j + s];
        __syncthreads();
    }
    if (j == 0) out[gid] = red[0] + b2[0];
}

extern "C" void kernel_launch(void* const* d_in, const int* in_sizes, int n_in,
                              void* d_out, int out_size, void* d_ws, size_t ws_size,
                              hipStream_t stream) {
    const float* x       = (const float*)d_in[0];
    const float* ea      = (const float*)d_in[1];
    const float* W_emb   = (const float*)d_in[2];
    const float* b_emb   = (const float*)d_in[3];
    const float* Wf      = (const float*)d_in[4];
    const float* bf      = (const float*)d_in[5];
    const float* Ws      = (const float*)d_in[6];
    const float* bs      = (const float*)d_in[7];
    const float* bn_g    = (const float*)d_in[8];
    const float* bn_b    = (const float*)d_in[9];
    const float* W1      = (const float*)d_in[10];
    const float* b1      = (const float*)d_in[11];
    const float* W2      = (const float*)d_in[12];
    const float* b2      = (const float*)d_in[13];
    const int*   ei      = (const int*)d_in[14];
    const int*   batch   = (const int*)d_in[15];
    float* out = (float*)d_out;

    char* wsb = (char*)d_ws;
    size_t off = 0;
    auto alloc = [&](size_t bytes) { char* p = wsb + off; off += (bytes + 255) & ~(size_t)255; return p; };
    float*        h        = (float*)alloc((size_t)N_NODES * 64 * 4);
    float*        agg      = (float*)alloc((size_t)N_NODES * 64 * 4);
    unsigned int* Pi       = (unsigned int*)alloc((size_t)N_NODES * 64 * 4);
    unsigned int* Pj       = (unsigned int*)alloc((size_t)N_NODES * 64 * 4);
    int*          edesc    = (int*)alloc((size_t)(N_EDGES + 16) * 4);
    int2*         staging  = (int2*)alloc((size_t)N_EDGES * 8);
    int*          meta     = (int*)alloc((1024 + PSLOT * 128) * 4);
    int*          bucketCnt    = meta;
    int*          flag         = meta + 512;
    float*        pstats       = (float*)(meta + 1024);
    int*          bucketBase   = (int*)alloc(520 * 4);
    int*          bucketCursor = (int*)alloc(512 * 4);
    int*          offs     = (int*)alloc((size_t)(N_NODES + 1) * 4);
    unsigned int* Tp       = (unsigned int*)alloc((size_t)NCONV * TS * 4);
    unsigned int* Bp       = (unsigned int*)alloc((size_t)NCONV * 8192 * 4);
    unsigned int* BpE      = (unsigned int*)alloc((size_t)64 * 64 * 4);
    float*        ss       = (float*)alloc(128 * 4);
    float*        g        = (float*)alloc((size_t)NGRAPH * 64 * 4);

    (void)hipMemsetAsync(meta, 0, (1024 + PSLOT * 128) * 4, stream);
    k_bhist<<<256, 256, 0, stream>>>(ei, bucketCnt, flag, bucketBase, bucketCursor, offs);
    k_psort1<<<(N_EDGES + S3CH - 1) / S3CH, 256, 0, stream>>>(ei, ea, bucketCursor, staging);
    k_psort2<<<NBKT, 256, 0, stream>>>(bucketBase, staging, edesc, offs);

    dim3 tg(163, NCONV);
    k_table2<<<tg, 256, 0, stream>>>(Wf, bf, Ws, bs, W_emb, Tp, Bp, BpE);
    k_embed_nodeP<<<(N_NODES + 63) / 64, 256, 0, stream>>>(x, BpE, b_emb, Bp, h, Pi, Pj);

    for (int l = 0; l < NCONV; ++l) {
        if (l > 0)
            k_nodeP_mfma<<<(N_NODES + 63) / 64, 256, 0, stream>>>(h, agg, ss, Bp, l, Pi, Pj);
        k_edge_sorted<<<N_NODES * 64 / 256, 256, 0, stream>>>(
            offs, edesc, Pi, Pj, Tp + (size_t)l * TS, agg, pstats);
        k_bnfinal<<<1, 128, 0, stream>>>(pstats, bn_g, bn_b, l, ss, g);
    }

    k_pool2<<<(N_NODES + 63) / 64, 256, 0, stream>>>(agg, ss, h, batch, g);
    k_head<<<NGRAPH, 128, 0, stream>>>(g, W1, b1, W2, b2, out);
}